// Round 1
// baseline (823.704 us; speedup 1.0000x reference)
//
#include <hip/hip_runtime.h>

#define TPB 256

static constexpr int B_ = 32;
static constexpr int C_ = 128;
static constexpr int N_ = 1024;
static constexpr int K_ = 9;
static constexpr int CN_ = C_ * N_;
static constexpr float INFV = 1.0e10f;
static constexpr float EPS_ = 1e-8f;

// ws layout (float slots)
static constexpr size_t XN_OFF  = 0;                            // xn  [B][C][N]
static constexpr size_t XT_OFF  = (size_t)B_ * CN_;             // xt  [B][N][C]
static constexpr size_t WRE_OFF = XT_OFF + (size_t)B_ * CN_;    // Wre [K][C][C_out]
static constexpr size_t IDX_OFF = WRE_OFF + (size_t)K_ * C_ * C_; // idx [B][N][K] (int32)

// ---------------------------------------------------------------------------
// 1) xn[b][c][n] = x[b][c][n] / (||x[b][:,n]|| + eps)   (matches ref rounding)
// ---------------------------------------------------------------------------
__global__ __launch_bounds__(TPB) void norm_xn_kernel(const float* __restrict__ x,
                                                      float* __restrict__ xn) {
    int t = blockIdx.x * TPB + threadIdx.x;        // 0..32767  (b,n)
    int b = t >> 10, n = t & (N_ - 1);
    const float* p = x + (size_t)b * CN_ + n;
    float ss = 0.f;
    #pragma unroll 8
    for (int c = 0; c < C_; ++c) { float v = p[(size_t)c * N_]; ss += v * v; }
    float nrm = sqrtf(ss) + EPS_;
    float* q = xn + (size_t)b * CN_ + n;
    #pragma unroll 8
    for (int c = 0; c < C_; ++c) q[(size_t)c * N_] = p[(size_t)c * N_] / nrm;
}

// ---------------------------------------------------------------------------
// 2) xt[b][n][c] = x[b][c][n]   (token-major copy for the gather)
// ---------------------------------------------------------------------------
__global__ __launch_bounds__(TPB) void transpose_kernel(const float* __restrict__ x,
                                                        float* __restrict__ xt) {
    __shared__ float lds[128][65];                  // +1 pad: conflict-free
    int b = blockIdx.x >> 4, n0 = (blockIdx.x & 15) << 6;
    const float* src = x + (size_t)b * CN_ + n0;
    #pragma unroll 4
    for (int i = 0; i < 32; ++i) {
        int flat = i * TPB + threadIdx.x;
        int c = flat >> 6, nn = flat & 63;
        lds[c][nn] = src[(size_t)c * N_ + nn];
    }
    __syncthreads();
    float* dst = xt + (size_t)b * CN_ + (size_t)n0 * C_;
    #pragma unroll 4
    for (int i = 0; i < 32; ++i) {
        int flat = i * TPB + threadIdx.x;
        int nn = flat >> 7, c = flat & 127;
        dst[(size_t)nn * C_ + c] = lds[c][nn];
    }
}

// ---------------------------------------------------------------------------
// 3) Wre[k][c][o] = W[o][c][k]   (k-major reorder of the conv weight)
// ---------------------------------------------------------------------------
__global__ __launch_bounds__(TPB) void wre_kernel(const float* __restrict__ W,
                                                  float* __restrict__ Wre) {
    int t = blockIdx.x * TPB + threadIdx.x;        // 0..147455
    int k = t / (C_ * C_);
    int rem = t - k * (C_ * C_);
    int c = rem >> 7, o = rem & 127;
    Wre[t] = W[(size_t)o * (C_ * K_) + c * K_ + k];
}

// ---------------------------------------------------------------------------
// 4) similarity GEMM (fp32) + exact stable top-9 per row
//    block: batch b, 128 rows; iterate 8 token-tiles of 128
//    thread (tr,tc): 8 rows x 8 tokens, tokens split {4tc..4tc+3, 64+4tc..}
// ---------------------------------------------------------------------------
__global__ __launch_bounds__(TPB, 1) void sim_topk_kernel(const float* __restrict__ xn,
                                                          int* __restrict__ idxo) {
    __shared__ float rowT[C_][128];                 // [c][row]       64 KB
    __shared__ float tokB[128 * 132];               // [c][tok] / sim[row][tok] 67.5 KB
    const int tid = threadIdx.x;
    const int b = blockIdx.x >> 3;
    const int n0 = (blockIdx.x & 7) << 7;
    const float* xb = xn + (size_t)b * CN_;

    #pragma unroll 4
    for (int i = 0; i < 64; ++i) {
        int flat = i * TPB + tid;
        int c = flat >> 7, r = flat & 127;
        rowT[c][r] = xb[(size_t)c * N_ + n0 + r];
    }

    const int tr = tid >> 4, tc = tid & 15;
    float val[9]; int id[9];
    #pragma unroll
    for (int p = 0; p < 9; ++p) { val[p] = -1e30f; id[p] = -1; }
    const int gn = n0 + tid;                        // row owned by scan thread

    for (int mt = 0; mt < 8; ++mt) {
        const int m0 = mt << 7;
        __syncthreads();                            // prev scan done
        #pragma unroll 4
        for (int i = 0; i < 64; ++i) {
            int flat = i * TPB + tid;
            int c = flat >> 7, m = flat & 127;
            tokB[c * 132 + m] = xb[(size_t)c * N_ + m0 + m];
        }
        __syncthreads();

        float acc[8][8];
        #pragma unroll
        for (int i = 0; i < 8; ++i)
            #pragma unroll
            for (int j = 0; j < 8; ++j) acc[i][j] = 0.f;

        for (int c = 0; c < C_; ++c) {
            float4 a0 = *(const float4*)&rowT[c][8 * tr];
            float4 a1 = *(const float4*)&rowT[c][8 * tr + 4];
            float4 b0 = *(const float4*)&tokB[c * 132 + 4 * tc];
            float4 b1 = *(const float4*)&tokB[c * 132 + 4 * tc + 64];
            float av[8] = {a0.x, a0.y, a0.z, a0.w, a1.x, a1.y, a1.z, a1.w};
            float bv[8] = {b0.x, b0.y, b0.z, b0.w, b1.x, b1.y, b1.z, b1.w};
            #pragma unroll
            for (int i = 0; i < 8; ++i)
                #pragma unroll
                for (int j = 0; j < 8; ++j)
                    acc[i][j] = fmaf(av[i], bv[j], acc[i][j]);
        }
        __syncthreads();                            // done reading tokB as B-tile
        // dump sims: row 8tr+i, cols {4tc..4tc+3} and {64+4tc..}
        #pragma unroll
        for (int i = 0; i < 8; ++i) {
            *(float4*)&tokB[(8 * tr + i) * 132 + 4 * tc] =
                make_float4(acc[i][0], acc[i][1], acc[i][2], acc[i][3]);
            *(float4*)&tokB[(8 * tr + i) * 132 + 64 + 4 * tc] =
                make_float4(acc[i][4], acc[i][5], acc[i][6], acc[i][7]);
        }
        __syncthreads();
        if (tid < 128) {                            // one thread per row
            const float* srow = &tokB[tid * 132];
            for (int q = 0; q < 32; ++q) {
                float4 v4 = *(const float4*)(srow + 4 * q);
                const int gm0 = m0 + 4 * q;
                float mx = fmaxf(fmaxf(v4.x, v4.y), fmaxf(v4.z, v4.w));
                bool diag = ((unsigned)(gn - gm0) < 4u);
                if (mx <= val[8] && !diag) continue;   // tie loses (gm > all ids)
                float vv[4] = {v4.x, v4.y, v4.z, v4.w};
                #pragma unroll
                for (int j = 0; j < 4; ++j) {
                    float v = vv[j]; int gm = gm0 + j;
                    if (gm == gn) v = INFV;            // self-similarity = +INF
                    bool bp[9];
                    #pragma unroll
                    for (int p = 0; p < 9; ++p)
                        bp[p] = (v > val[p]) || (v == val[p] && gm < id[p]);
                    if (bp[8]) {
                        #pragma unroll
                        for (int p = 8; p >= 1; --p) {
                            val[p] = bp[p - 1] ? val[p - 1] : (bp[p] ? v  : val[p]);
                            id[p]  = bp[p - 1] ? id[p - 1]  : (bp[p] ? gm : id[p]);
                        }
                        if (bp[0]) { val[0] = v; id[0] = gm; }
                    }
                }
            }
        }
    }
    if (tid < 128) {
        int* op = idxo + ((size_t)b * N_ + n0 + tid) * K_;
        #pragma unroll
        for (int p = 0; p < 9; ++p) op[p] = id[p];
    }
}

// ---------------------------------------------------------------------------
// 5) gather + conv contraction: out[b][o][n] = sum_{k,c} xt[b][idx[n][k]][c] * Wre[k][c][o]
//    block: batch b, 128 tokens, all 128 o; per-thread 8o x 8n
// ---------------------------------------------------------------------------
__global__ __launch_bounds__(TPB, 1) void conv_kernel(const float* __restrict__ xt,
                                                      const float* __restrict__ Wre,
                                                      const int* __restrict__ idxi,
                                                      float* __restrict__ out) {
    __shared__ float Wk[C_ * 128];                  // [c][o]   64 KB
    __shared__ float G[C_ * 132];                   // [c][tok] 67.5 KB
    const int tid = threadIdx.x;
    const int b = blockIdx.x >> 3;
    const int n0 = (blockIdx.x & 7) << 7;
    const int to = tid >> 4, tn = tid & 15;
    const float* xtb = xt + (size_t)b * CN_;

    float acc[8][8];
    #pragma unroll
    for (int i = 0; i < 8; ++i)
        #pragma unroll
        for (int j = 0; j < 8; ++j) acc[i][j] = 0.f;

    for (int k = 0; k < K_; ++k) {
        __syncthreads();                            // prev compute done
        #pragma unroll 4
        for (int i = 0; i < 64; ++i) {
            int flat = i * TPB + tid;
            Wk[flat] = Wre[(size_t)k * (C_ * C_) + flat];
        }
        {   // gather 128 tokens' features, transposed into [c][tok]
            int tt = tid >> 1, half = tid & 1;
            int j = idxi[((size_t)b * N_ + n0 + tt) * K_ + k];
            const float4* src = (const float4*)(xtb + (size_t)j * C_ + half * 64);
            #pragma unroll
            for (int qq = 0; qq < 16; ++qq) {
                float4 v = src[qq];
                int c0 = half * 64 + 4 * qq;
                G[(c0 + 0) * 132 + tt] = v.x;
                G[(c0 + 1) * 132 + tt] = v.y;
                G[(c0 + 2) * 132 + tt] = v.z;
                G[(c0 + 3) * 132 + tt] = v.w;
            }
        }
        __syncthreads();
        for (int c = 0; c < C_; ++c) {
            float4 a0 = *(const float4*)&Wk[c * 128 + 8 * to];
            float4 a1 = *(const float4*)&Wk[c * 128 + 8 * to + 4];
            float4 b0 = *(const float4*)&G[c * 132 + 4 * tn];
            float4 b1 = *(const float4*)&G[c * 132 + 4 * tn + 64];
            float av[8] = {a0.x, a0.y, a0.z, a0.w, a1.x, a1.y, a1.z, a1.w};
            float bv[8] = {b0.x, b0.y, b0.z, b0.w, b1.x, b1.y, b1.z, b1.w};
            #pragma unroll
            for (int i = 0; i < 8; ++i)
                #pragma unroll
                for (int j = 0; j < 8; ++j)
                    acc[i][j] = fmaf(av[i], bv[j], acc[i][j]);
        }
    }
    float* ob = out + (size_t)b * C_ * N_;
    #pragma unroll
    for (int i = 0; i < 8; ++i) {
        int o = 8 * to + i;
        *(float4*)&ob[(size_t)o * N_ + n0 + 4 * tn] =
            make_float4(acc[i][0], acc[i][1], acc[i][2], acc[i][3]);
        *(float4*)&ob[(size_t)o * N_ + n0 + 64 + 4 * tn] =
            make_float4(acc[i][4], acc[i][5], acc[i][6], acc[i][7]);
    }
}

// ---------------------------------------------------------------------------
extern "C" void kernel_launch(void* const* d_in, const int* in_sizes, int n_in,
                              void* d_out, int out_size, void* d_ws, size_t ws_size,
                              hipStream_t stream) {
    (void)in_sizes; (void)n_in; (void)out_size; (void)ws_size;
    const float* x = (const float*)d_in[0];
    const float* W = (const float*)d_in[1];
    float* out = (float*)d_out;
    float* ws  = (float*)d_ws;
    float* xn  = ws + XN_OFF;
    float* xt  = ws + XT_OFF;
    float* Wre = ws + WRE_OFF;
    int*   idx = (int*)(ws + IDX_OFF);

    norm_xn_kernel<<<(B_ * N_) / TPB, TPB, 0, stream>>>(x, xn);
    transpose_kernel<<<B_ * 16, TPB, 0, stream>>>(x, xt);
    wre_kernel<<<(K_ * C_ * C_) / TPB, TPB, 0, stream>>>(W, Wre);
    sim_topk_kernel<<<B_ * 8, TPB, 0, stream>>>(xn, idx);
    conv_kernel<<<B_ * 8, TPB, 0, stream>>>(xt, Wre, idx, out);
}

// Round 2
// 598.309 us; speedup vs baseline: 1.3767x; 1.3767x over previous
//
#include <hip/hip_runtime.h>
#include <hip/hip_bf16.h>

#define TPB 256

static constexpr int B_ = 32;
static constexpr int C_ = 128;
static constexpr int N_ = 1024;
static constexpr int K_ = 9;
static constexpr int CN_ = C_ * N_;
static constexpr float INFV = 1.0e10f;
static constexpr float EPS_ = 1e-8f;

// ws layout (float slots)
static constexpr size_t XN_OFF   = 0;                               // xn [B][C][N] fp32
static constexpr size_t CAND_OFF = (size_t)B_ * CN_;                // CV floats | CI ints; xtb bf16 aliases here
static constexpr size_t CV_OFF   = CAND_OFF;                        // [B][N][4][9] float
static constexpr size_t CI_OFF   = CAND_OFF + (size_t)B_ * N_ * 36; // [B][N][4][9] int
static constexpr size_t WRE_OFF  = CAND_OFF + 2 * (size_t)B_ * N_ * 36;
static constexpr size_t IDX_OFF  = WRE_OFF + (size_t)K_ * C_ * C_;  // [B][N][9] int

// exact stable top-9 insert: beats slot p if (v > val) or (v == val and smaller idx)
#define INSERT9(Vv, Ii, vexpr, gmexpr)                                     \
    {                                                                       \
        float _v = (vexpr); int _gm = (gmexpr);                             \
        bool bp[9];                                                         \
        _Pragma("unroll")                                                   \
        for (int _p = 0; _p < 9; ++_p)                                      \
            bp[_p] = (_v > Vv[_p]) || (_v == Vv[_p] && _gm < Ii[_p]);       \
        if (bp[8]) {                                                        \
            _Pragma("unroll")                                               \
            for (int _p = 8; _p >= 1; --_p) {                               \
                Vv[_p] = bp[_p - 1] ? Vv[_p - 1] : (bp[_p] ? _v  : Vv[_p]); \
                Ii[_p] = bp[_p - 1] ? Ii[_p - 1] : (bp[_p] ? _gm : Ii[_p]); \
            }                                                               \
            if (bp[0]) { Vv[0] = _v; Ii[0] = _gm; }                         \
        }                                                                   \
    }

// ---------------------------------------------------------------------------
// 1) xn[b][c][n] = x[b][c][n] / (||x[b][:,n]|| + eps)
// ---------------------------------------------------------------------------
__global__ __launch_bounds__(TPB) void norm_xn_kernel(const float* __restrict__ x,
                                                      float* __restrict__ xn) {
    int t = blockIdx.x * TPB + threadIdx.x;
    int b = t >> 10, n = t & (N_ - 1);
    const float* p = x + (size_t)b * CN_ + n;
    float ss = 0.f;
    #pragma unroll 8
    for (int c = 0; c < C_; ++c) { float v = p[(size_t)c * N_]; ss += v * v; }
    float nrm = sqrtf(ss) + EPS_;
    float* q = xn + (size_t)b * CN_ + n;
    #pragma unroll 8
    for (int c = 0; c < C_; ++c) q[(size_t)c * N_] = p[(size_t)c * N_] / nrm;
}

// ---------------------------------------------------------------------------
// 2) xtb[b][n][c] = bf16(x[b][c][n])   (token-major bf16 copy for conv gather)
// ---------------------------------------------------------------------------
__global__ __launch_bounds__(TPB) void transpose_bf16_kernel(const float* __restrict__ x,
                                                             __hip_bfloat16* __restrict__ xtb) {
    __shared__ float lds[128][65];
    int b = blockIdx.x >> 4, n0 = (blockIdx.x & 15) << 6;
    const float* src = x + (size_t)b * CN_ + n0;
    #pragma unroll 4
    for (int i = 0; i < 32; ++i) {
        int flat = i * TPB + threadIdx.x;
        int c = flat >> 6, nn = flat & 63;
        lds[c][nn] = src[(size_t)c * N_ + nn];
    }
    __syncthreads();
    __hip_bfloat16* dst = xtb + (size_t)b * CN_ + (size_t)n0 * C_;
    #pragma unroll 4
    for (int i = 0; i < 32; ++i) {
        int flat = i * TPB + threadIdx.x;
        int nn = flat >> 7, c = flat & 127;
        dst[(size_t)nn * C_ + c] = __float2bfloat16(lds[c][nn]);
    }
}

// ---------------------------------------------------------------------------
// 3) Wre[k][c][o] = W[o][c][k]
// ---------------------------------------------------------------------------
__global__ __launch_bounds__(TPB) void wre_kernel(const float* __restrict__ W,
                                                  float* __restrict__ Wre) {
    int t = blockIdx.x * TPB + threadIdx.x;
    int k = t / (C_ * C_);
    int rem = t - k * (C_ * C_);
    int c = rem >> 7, o = rem & 127;
    Wre[t] = W[(size_t)o * (C_ * K_) + c * K_ + k];
}

// ---------------------------------------------------------------------------
// 4) sim GEMM (fp32, c-chunked LDS, 3 blocks/CU) + per-block partial top-9
//    block = (b, it: 128 rows, jp: 256 cols as two 128-col passes)
//    emits one stable top-9 candidate list per (row, jp)
// ---------------------------------------------------------------------------
__global__ __launch_bounds__(TPB, 3) void sim_gemm_kernel(const float* __restrict__ xn,
                                                          float* __restrict__ cv,
                                                          int* __restrict__ ci) {
    __shared__ __align__(16) float lds[8448];   // As[0..4096) Bs[4224..8448); scanbuf aliases all
    __shared__ float mv[64][9];
    __shared__ int   mi[64][9];
    float* As = lds;                            // [c][row]  32 x 128
    float* Bs = lds + 4224;                     // [c][m]    32 x 132
    float* scanbuf = lds;                       // [64][132]

    const int tid = threadIdx.x;
    const int jp = blockIdx.x & 3;
    const int it = (blockIdx.x >> 2) & 7;
    const int b  = blockIdx.x >> 5;
    const int n0 = it << 7;
    const float* xb = xn + (size_t)b * CN_;
    const int tr = tid >> 4, tc = tid & 15;
    const int rl = tid >> 1;                    // owned row (local 0..127)
    const int sh = tid & 1;                     // half of the row this thread scans
    const int sg = tid >> 7;                    // scan group membership
    const int sr6 = rl & 63;
    const int grow = n0 + rl;                   // owned global row

    float val[9]; int id[9];
    #pragma unroll
    for (int p = 0; p < 9; ++p) { val[p] = -1e30f; id[p] = -1; }

    for (int ps = 0; ps < 2; ++ps) {
        const int m0 = ((jp << 1) + ps) << 7;
        float acc[8][8];
        #pragma unroll
        for (int i = 0; i < 8; ++i)
            #pragma unroll
            for (int j = 0; j < 8; ++j) acc[i][j] = 0.f;

        for (int cc = 0; cc < 4; ++cc) {
            const int c0 = cc << 5;
            __syncthreads();
            #pragma unroll
            for (int q = 0; q < 4; ++q) {
                int flat = (q << 8) + tid;
                int c = flat >> 5, nq = (flat & 31) << 2;
                const float* row = &xb[(size_t)(c0 + c) * N_];
                *(float4*)&As[c * 128 + nq] = *(const float4*)&row[n0 + nq];
                *(float4*)&Bs[c * 132 + nq] = *(const float4*)&row[m0 + nq];
            }
            __syncthreads();
            for (int c = 0; c < 32; ++c) {
                float4 a0 = *(const float4*)&As[c * 128 + 8 * tr];
                float4 a1 = *(const float4*)&As[c * 128 + 8 * tr + 4];
                float4 b0 = *(const float4*)&Bs[c * 132 + 4 * tc];
                float4 b1 = *(const float4*)&Bs[c * 132 + 64 + 4 * tc];
                float av[8] = {a0.x, a0.y, a0.z, a0.w, a1.x, a1.y, a1.z, a1.w};
                float bv[8] = {b0.x, b0.y, b0.z, b0.w, b1.x, b1.y, b1.z, b1.w};
                #pragma unroll
                for (int i = 0; i < 8; ++i)
                    #pragma unroll
                    for (int j = 0; j < 8; ++j)
                        acc[i][j] = fmaf(av[i], bv[j], acc[i][j]);
            }
        }

        // scan in two 64-row groups; dumpers == scanners per group
        for (int g = 0; g < 2; ++g) {
            __syncthreads();
            if ((tr >> 3) == g) {
                int rbase = (tr & 7) << 3;
                #pragma unroll
                for (int i = 0; i < 8; ++i) {
                    *(float4*)&scanbuf[(rbase + i) * 132 + 4 * tc] =
                        make_float4(acc[i][0], acc[i][1], acc[i][2], acc[i][3]);
                    *(float4*)&scanbuf[(rbase + i) * 132 + 64 + 4 * tc] =
                        make_float4(acc[i][4], acc[i][5], acc[i][6], acc[i][7]);
                }
            }
            __syncthreads();
            if (sg == g) {
                float lv[9]; int li[9];
                #pragma unroll
                for (int p = 0; p < 9; ++p) { lv[p] = -1e30f; li[p] = -1; }
                const float* srow = &scanbuf[sr6 * 132 + (sh << 6)];
                const int colbase = m0 + (sh << 6);
                for (int q = 0; q < 16; ++q) {
                    float4 v4 = *(const float4*)(srow + 4 * q);
                    const int gm0 = colbase + 4 * q;
                    float mx = fmaxf(fmaxf(v4.x, v4.y), fmaxf(v4.z, v4.w));
                    bool diag = ((unsigned)(grow - gm0) < 4u);
                    if (mx < lv[8] && !diag) continue;   // strict <: exact ties still processed
                    float vv[4] = {v4.x, v4.y, v4.z, v4.w};
                    #pragma unroll
                    for (int j = 0; j < 4; ++j) {
                        float v = vv[j]; int gm = gm0 + j;
                        if (gm == grow) v = INFV;        // self-similarity = +INF
                        INSERT9(lv, li, v, gm)
                    }
                }
                if (sh) {
                    #pragma unroll
                    for (int p = 0; p < 9; ++p) { mv[sr6][p] = lv[p]; mi[sr6][p] = li[p]; }
                } else {
                    #pragma unroll
                    for (int p = 0; p < 9; ++p) INSERT9(val, id, lv[p], li[p])
                }
            }
            __syncthreads();
            if (sg == g && sh == 0) {
                #pragma unroll
                for (int p = 0; p < 9; ++p) INSERT9(val, id, mv[sr6][p], mi[sr6][p])
            }
        }
    }

    if (sh == 0) {
        size_t base = (((size_t)b * N_ + grow) * 4 + jp) * 9;
        #pragma unroll
        for (int p = 0; p < 9; ++p) { cv[base + p] = val[p]; ci[base + p] = id[p]; }
    }
}

// ---------------------------------------------------------------------------
// 5) merge 4 partial top-9 lists -> final top-9 indices per row
// ---------------------------------------------------------------------------
__global__ __launch_bounds__(TPB) void topk_merge_kernel(const float* __restrict__ cv,
                                                         const int* __restrict__ ci,
                                                         int* __restrict__ idxo) {
    int t = blockIdx.x * TPB + threadIdx.x;     // row id, 0..32767
    float val[9]; int id[9];
    #pragma unroll
    for (int p = 0; p < 9; ++p) { val[p] = -1e30f; id[p] = -1; }
    const float* pv = cv + (size_t)t * 36;
    const int*   pi = ci + (size_t)t * 36;
    for (int s = 0; s < 36; ++s) {
        float v = pv[s]; int gm = pi[s];
        bool worse = (v < val[8]) || (v == val[8] && gm > id[8]);
        if (!worse) INSERT9(val, id, v, gm)
    }
    int* op = idxo + (size_t)t * 9;
    #pragma unroll
    for (int p = 0; p < 9; ++p) op[p] = id[p];
}

// ---------------------------------------------------------------------------
// 6) gather + conv: out[b][o][n] = sum_{k,c} xtb[b][idx[n][k]][c] * Wre[k][c][o]
// ---------------------------------------------------------------------------
__global__ __launch_bounds__(TPB, 1) void conv_kernel(const __hip_bfloat16* __restrict__ xtb,
                                                      const float* __restrict__ Wre,
                                                      const int* __restrict__ idxi,
                                                      float* __restrict__ out) {
    __shared__ float Wk[C_ * 128];              // [c][o]
    __shared__ float G[C_ * 132];               // [c][tok]
    const int tid = threadIdx.x;
    const int b = blockIdx.x >> 3;
    const int n0 = (blockIdx.x & 7) << 7;
    const int to = tid >> 4, tn = tid & 15;
    const __hip_bfloat16* xb = xtb + (size_t)b * CN_;

    float acc[8][8];
    #pragma unroll
    for (int i = 0; i < 8; ++i)
        #pragma unroll
        for (int j = 0; j < 8; ++j) acc[i][j] = 0.f;

    for (int k = 0; k < K_; ++k) {
        __syncthreads();
        #pragma unroll
        for (int q = 0; q < 16; ++q) {
            int f4 = (q << 8) + tid;
            *(float4*)&Wk[4 * f4] = *(const float4*)&Wre[(size_t)k * (C_ * C_) + 4 * f4];
        }
        {   // gather 128 tokens' bf16 features -> fp32 [c][tok]
            int tt = tid >> 1, half = tid & 1;
            int j = idxi[((size_t)b * N_ + n0 + tt) * K_ + k];
            const uint4* src = (const uint4*)(xb + (size_t)j * C_ + half * 64);
            #pragma unroll
            for (int qq = 0; qq < 8; ++qq) {
                uint4 w = src[qq];
                int c0 = half * 64 + 8 * qq;
                G[(c0 + 0) * 132 + tt] = __uint_as_float(w.x << 16);
                G[(c0 + 1) * 132 + tt] = __uint_as_float(w.x & 0xffff0000u);
                G[(c0 + 2) * 132 + tt] = __uint_as_float(w.y << 16);
                G[(c0 + 3) * 132 + tt] = __uint_as_float(w.y & 0xffff0000u);
                G[(c0 + 4) * 132 + tt] = __uint_as_float(w.z << 16);
                G[(c0 + 5) * 132 + tt] = __uint_as_float(w.z & 0xffff0000u);
                G[(c0 + 6) * 132 + tt] = __uint_as_float(w.w << 16);
                G[(c0 + 7) * 132 + tt] = __uint_as_float(w.w & 0xffff0000u);
            }
        }
        __syncthreads();
        for (int c = 0; c < C_; ++c) {
            float4 a0 = *(const float4*)&Wk[c * 128 + 8 * to];
            float4 a1 = *(const float4*)&Wk[c * 128 + 8 * to + 4];
            float4 b0 = *(const float4*)&G[c * 132 + 4 * tn];
            float4 b1 = *(const float4*)&G[c * 132 + 64 + 4 * tn];
            float av[8] = {a0.x, a0.y, a0.z, a0.w, a1.x, a1.y, a1.z, a1.w};
            float bv[8] = {b0.x, b0.y, b0.z, b0.w, b1.x, b1.y, b1.z, b1.w};
            #pragma unroll
            for (int i = 0; i < 8; ++i)
                #pragma unroll
                for (int j = 0; j < 8; ++j)
                    acc[i][j] = fmaf(av[i], bv[j], acc[i][j]);
        }
    }
    float* ob = out + (size_t)b * C_ * N_;
    #pragma unroll
    for (int i = 0; i < 8; ++i) {
        int o = 8 * to + i;
        *(float4*)&ob[(size_t)o * N_ + n0 + 4 * tn] =
            make_float4(acc[i][0], acc[i][1], acc[i][2], acc[i][3]);
        *(float4*)&ob[(size_t)o * N_ + n0 + 64 + 4 * tn] =
            make_float4(acc[i][4], acc[i][5], acc[i][6], acc[i][7]);
    }
}

// ---------------------------------------------------------------------------
extern "C" void kernel_launch(void* const* d_in, const int* in_sizes, int n_in,
                              void* d_out, int out_size, void* d_ws, size_t ws_size,
                              hipStream_t stream) {
    (void)in_sizes; (void)n_in; (void)out_size; (void)ws_size;
    const float* x = (const float*)d_in[0];
    const float* W = (const float*)d_in[1];
    float* out = (float*)d_out;
    float* ws  = (float*)d_ws;

    float* xn  = ws + XN_OFF;
    float* cv  = ws + CV_OFF;
    int*   ci  = (int*)(ws + CI_OFF);
    __hip_bfloat16* xtb = (__hip_bfloat16*)(ws + CAND_OFF);  // aliases cv/ci (disjoint lifetime)
    float* Wre = ws + WRE_OFF;
    int*   idx = (int*)(ws + IDX_OFF);

    norm_xn_kernel<<<(B_ * N_) / TPB, TPB, 0, stream>>>(x, xn);
    wre_kernel<<<(K_ * C_ * C_) / TPB, TPB, 0, stream>>>(W, Wre);
    sim_gemm_kernel<<<B_ * 8 * 4, TPB, 0, stream>>>(xn, cv, ci);
    topk_merge_kernel<<<(B_ * N_) / TPB, TPB, 0, stream>>>(cv, ci, idx);
    transpose_bf16_kernel<<<B_ * 16, TPB, 0, stream>>>(x, xtb);  // after merge: xtb overwrites cand
    conv_kernel<<<B_ * 8, TPB, 0, stream>>>(xtb, Wre, idx, out);
}

// Round 3
// 598.090 us; speedup vs baseline: 1.3772x; 1.0004x over previous
//
#include <hip/hip_runtime.h>
#include <hip/hip_bf16.h>

#define TPB 256

static constexpr int B_ = 32;
static constexpr int C_ = 128;
static constexpr int N_ = 1024;
static constexpr int K_ = 9;
static constexpr int CN_ = C_ * N_;
static constexpr float INFV = 1.0e10f;
static constexpr float EPS_ = 1e-8f;

// ws layout (float slots)
static constexpr size_t XN_OFF   = 0;                               // xn [B][C][N] fp32
static constexpr size_t CAND_OFF = (size_t)B_ * CN_;                // CV floats | CI ints; xtb bf16 aliases here
static constexpr size_t CV_OFF   = CAND_OFF;                        // [B][N][4][9] float
static constexpr size_t CI_OFF   = CAND_OFF + (size_t)B_ * N_ * 36; // [B][N][4][9] int
static constexpr size_t WRE_OFF  = CAND_OFF + 2 * (size_t)B_ * N_ * 36;
static constexpr size_t IDX_OFF  = WRE_OFF + (size_t)K_ * C_ * C_;  // [B][N][9] int

// exact stable top-9 insert: beats slot p if (v > val) or (v == val and smaller idx)
#define INSERT9(Vv, Ii, vexpr, gmexpr)                                     \
    {                                                                       \
        float _v = (vexpr); int _gm = (gmexpr);                             \
        bool bp[9];                                                         \
        _Pragma("unroll")                                                   \
        for (int _p = 0; _p < 9; ++_p)                                      \
            bp[_p] = (_v > Vv[_p]) || (_v == Vv[_p] && _gm < Ii[_p]);       \
        if (bp[8]) {                                                        \
            _Pragma("unroll")                                               \
            for (int _p = 8; _p >= 1; --_p) {                               \
                Vv[_p] = bp[_p - 1] ? Vv[_p - 1] : (bp[_p] ? _v  : Vv[_p]); \
                Ii[_p] = bp[_p - 1] ? Ii[_p - 1] : (bp[_p] ? _gm : Ii[_p]); \
            }                                                               \
            if (bp[0]) { Vv[0] = _v; Ii[0] = _gm; }                         \
        }                                                                   \
    }

// ---------------------------------------------------------------------------
// 1) xn[b][c][n] = x[b][c][n] / (||x[b][:,n]|| + eps)
// ---------------------------------------------------------------------------
__global__ __launch_bounds__(TPB) void norm_xn_kernel(const float* __restrict__ x,
                                                      float* __restrict__ xn) {
    int t = blockIdx.x * TPB + threadIdx.x;
    int b = t >> 10, n = t & (N_ - 1);
    const float* p = x + (size_t)b * CN_ + n;
    float ss = 0.f;
    #pragma unroll 8
    for (int c = 0; c < C_; ++c) { float v = p[(size_t)c * N_]; ss += v * v; }
    float nrm = sqrtf(ss) + EPS_;
    float* q = xn + (size_t)b * CN_ + n;
    #pragma unroll 8
    for (int c = 0; c < C_; ++c) q[(size_t)c * N_] = p[(size_t)c * N_] / nrm;
}

// ---------------------------------------------------------------------------
// 2) xtb[b][n][c] = bf16(x[b][c][n])
// ---------------------------------------------------------------------------
__global__ __launch_bounds__(TPB) void transpose_bf16_kernel(const float* __restrict__ x,
                                                             __hip_bfloat16* __restrict__ xtb) {
    __shared__ float lds[128][65];
    int b = blockIdx.x >> 4, n0 = (blockIdx.x & 15) << 6;
    const float* src = x + (size_t)b * CN_ + n0;
    #pragma unroll 4
    for (int i = 0; i < 32; ++i) {
        int flat = i * TPB + threadIdx.x;
        int c = flat >> 6, nn = flat & 63;
        lds[c][nn] = src[(size_t)c * N_ + nn];
    }
    __syncthreads();
    __hip_bfloat16* dst = xtb + (size_t)b * CN_ + (size_t)n0 * C_;
    #pragma unroll 4
    for (int i = 0; i < 32; ++i) {
        int flat = i * TPB + threadIdx.x;
        int nn = flat >> 7, c = flat & 127;
        dst[(size_t)nn * C_ + c] = __float2bfloat16(lds[c][nn]);
    }
}

// ---------------------------------------------------------------------------
// 3) Wre[k][c][o] = W[o][c][k]
// ---------------------------------------------------------------------------
__global__ __launch_bounds__(TPB) void wre_kernel(const float* __restrict__ W,
                                                  float* __restrict__ Wre) {
    int t = blockIdx.x * TPB + threadIdx.x;
    int k = t / (C_ * C_);
    int rem = t - k * (C_ * C_);
    int c = rem >> 7, o = rem & 127;
    Wre[t] = W[(size_t)o * (C_ * K_) + c * K_ + k];
}

// ---------------------------------------------------------------------------
// 4) sim GEMM (fp32, pipelined LDS->reg) + per-block partial top-9
//    Math order identical to round 2 -> bitwise-identical sims/ranking.
// ---------------------------------------------------------------------------
__global__ __launch_bounds__(TPB, 4) void sim_gemm_kernel(const float* __restrict__ xn,
                                                          float* __restrict__ cv,
                                                          int* __restrict__ ci) {
    __shared__ __align__(16) float lds[8448];   // As[0..4096) Bs[4224..8448); scanbuf aliases
    __shared__ float mv[64][9];
    __shared__ int   mi[64][9];
    float* As = lds;                            // [c][row]  32 x 128
    float* Bs = lds + 4224;                     // [c][m]    32 x 132
    float* scanbuf = lds;                       // [64][132]

    const int tid = threadIdx.x;
    const int jp = blockIdx.x & 3;
    const int it = (blockIdx.x >> 2) & 7;
    const int b  = blockIdx.x >> 5;
    const int n0 = it << 7;
    const float* xb = xn + (size_t)b * CN_;
    const int tr = tid >> 4, tc = tid & 15;
    const int rl = tid >> 1;
    const int sh = tid & 1;
    const int sg = tid >> 7;
    const int sr6 = rl & 63;
    const int grow = n0 + rl;

    float val[9]; int id[9];
    #pragma unroll
    for (int p = 0; p < 9; ++p) { val[p] = -1e30f; id[p] = -1; }

    #pragma unroll 1
    for (int ps = 0; ps < 2; ++ps) {
        const int m0 = ((jp << 1) + ps) << 7;
        float acc[8][8];
        #pragma unroll
        for (int i = 0; i < 8; ++i)
            #pragma unroll
            for (int j = 0; j < 8; ++j) acc[i][j] = 0.f;

        #pragma unroll 1
        for (int cc = 0; cc < 4; ++cc) {
            const int c0 = cc << 5;
            __syncthreads();
            #pragma unroll
            for (int q = 0; q < 4; ++q) {
                int flat = (q << 8) + tid;
                int c = flat >> 5, nq = (flat & 31) << 2;
                const float* row = &xb[(size_t)(c0 + c) * N_];
                *(float4*)&As[c * 128 + nq] = *(const float4*)&row[n0 + nq];
                *(float4*)&Bs[c * 132 + nq] = *(const float4*)&row[m0 + nq];
            }
            __syncthreads();
            const float* Ap  = &As[8 * tr];
            const float* Bp0 = &Bs[4 * tc];
            const float* Bp1 = &Bs[64 + 4 * tc];
            float4 a0 = *(const float4*)(Ap);
            float4 a1 = *(const float4*)(Ap + 4);
            float4 b0 = *(const float4*)(Bp0);
            float4 b1 = *(const float4*)(Bp1);
            #pragma unroll
            for (int c = 0; c < 32; ++c) {
                const int cn = (c + 1) & 31;      // c=31 reloads c=0 (harmless)
                float4 na0 = *(const float4*)(Ap  + cn * 128);
                float4 na1 = *(const float4*)(Ap  + cn * 128 + 4);
                float4 nb0 = *(const float4*)(Bp0 + cn * 132);
                float4 nb1 = *(const float4*)(Bp1 + cn * 132);
                float av[8] = {a0.x, a0.y, a0.z, a0.w, a1.x, a1.y, a1.z, a1.w};
                float bv[8] = {b0.x, b0.y, b0.z, b0.w, b1.x, b1.y, b1.z, b1.w};
                #pragma unroll
                for (int i = 0; i < 8; ++i)
                    #pragma unroll
                    for (int j = 0; j < 8; ++j)
                        acc[i][j] = fmaf(av[i], bv[j], acc[i][j]);
                a0 = na0; a1 = na1; b0 = nb0; b1 = nb1;
            }
        }

        // scan in two 64-row groups (identical to round 2)
        #pragma unroll 1
        for (int g = 0; g < 2; ++g) {
            __syncthreads();
            if ((tr >> 3) == g) {
                int rbase = (tr & 7) << 3;
                #pragma unroll
                for (int i = 0; i < 8; ++i) {
                    *(float4*)&scanbuf[(rbase + i) * 132 + 4 * tc] =
                        make_float4(acc[i][0], acc[i][1], acc[i][2], acc[i][3]);
                    *(float4*)&scanbuf[(rbase + i) * 132 + 64 + 4 * tc] =
                        make_float4(acc[i][4], acc[i][5], acc[i][6], acc[i][7]);
                }
            }
            __syncthreads();
            if (sg == g) {
                float lv[9]; int li[9];
                #pragma unroll
                for (int p = 0; p < 9; ++p) { lv[p] = -1e30f; li[p] = -1; }
                const float* srow = &scanbuf[sr6 * 132 + (sh << 6)];
                const int colbase = m0 + (sh << 6);
                for (int q = 0; q < 16; ++q) {
                    float4 v4 = *(const float4*)(srow + 4 * q);
                    const int gm0 = colbase + 4 * q;
                    float mx = fmaxf(fmaxf(v4.x, v4.y), fmaxf(v4.z, v4.w));
                    bool diag = ((unsigned)(grow - gm0) < 4u);
                    if (mx < lv[8] && !diag) continue;
                    float vv[4] = {v4.x, v4.y, v4.z, v4.w};
                    #pragma unroll
                    for (int j = 0; j < 4; ++j) {
                        float v = vv[j]; int gm = gm0 + j;
                        if (gm == grow) v = INFV;
                        INSERT9(lv, li, v, gm)
                    }
                }
                if (sh) {
                    #pragma unroll
                    for (int p = 0; p < 9; ++p) { mv[sr6][p] = lv[p]; mi[sr6][p] = li[p]; }
                } else {
                    #pragma unroll
                    for (int p = 0; p < 9; ++p) INSERT9(val, id, lv[p], li[p])
                }
            }
            __syncthreads();
            if (sg == g && sh == 0) {
                #pragma unroll
                for (int p = 0; p < 9; ++p) INSERT9(val, id, mv[sr6][p], mi[sr6][p])
            }
        }
    }

    if (sh == 0) {
        size_t base = (((size_t)b * N_ + grow) * 4 + jp) * 9;
        #pragma unroll
        for (int p = 0; p < 9; ++p) { cv[base + p] = val[p]; ci[base + p] = id[p]; }
    }
}

// ---------------------------------------------------------------------------
// 5) merge 4 partial top-9 lists -> final top-9 indices per row
// ---------------------------------------------------------------------------
__global__ __launch_bounds__(TPB) void topk_merge_kernel(const float* __restrict__ cv,
                                                         const int* __restrict__ ci,
                                                         int* __restrict__ idxo) {
    int t = blockIdx.x * TPB + threadIdx.x;
    float val[9]; int id[9];
    #pragma unroll
    for (int p = 0; p < 9; ++p) { val[p] = -1e30f; id[p] = -1; }
    const float* pv = cv + (size_t)t * 36;
    const int*   pi = ci + (size_t)t * 36;
    for (int s = 0; s < 36; ++s) {
        float v = pv[s]; int gm = pi[s];
        bool worse = (v < val[8]) || (v == val[8] && gm > id[8]);
        if (!worse) INSERT9(val, id, v, gm)
    }
    int* op = idxo + (size_t)t * 9;
    #pragma unroll
    for (int p = 0; p < 9; ++p) op[p] = id[p];
}

// ---------------------------------------------------------------------------
// 6) zero d_out (conv accumulates atomically)
// ---------------------------------------------------------------------------
__global__ __launch_bounds__(TPB) void zero_out_kernel(float4* __restrict__ p, int n4) {
    int t = blockIdx.x * TPB + threadIdx.x;
    for (int i = t; i < n4; i += gridDim.x * TPB)
        p[i] = make_float4(0.f, 0.f, 0.f, 0.f);
}

// ---------------------------------------------------------------------------
// 7) conv, 3-way k-split: block (b, ntile, kg) accumulates k in [3kg,3kg+3)
//    out[b][o][n] += sum_{k,c} bf16(x)[b][idx[n][k]][c] * Wre[k][c][o]
// ---------------------------------------------------------------------------
__global__ __launch_bounds__(TPB, 4) void conv_kg_kernel(const __hip_bfloat16* __restrict__ xtb,
                                                         const float* __restrict__ Wre,
                                                         const int* __restrict__ idxi,
                                                         float* __restrict__ out) {
    __shared__ __align__(16) float Ws[32 * 128];   // [c][o]   16 KB
    __shared__ __align__(16) float Gs[32 * 132];   // [c][tok] 16.9 KB
    const int tid = threadIdx.x;
    const unsigned bx = blockIdx.x;
    const int kg = bx % 3;
    const int rest = bx / 3;
    const int it = rest & 7;
    const int b  = rest >> 3;
    const int n0 = it << 7;
    const int to = tid >> 4, tn = tid & 15;
    const __hip_bfloat16* xb = xtb + (size_t)b * CN_;

    float acc[8][8];
    #pragma unroll
    for (int i = 0; i < 8; ++i)
        #pragma unroll
        for (int j = 0; j < 8; ++j) acc[i][j] = 0.f;

    #pragma unroll 1
    for (int k = 3 * kg; k < 3 * kg + 3; ++k) {
        #pragma unroll 1
        for (int cc = 0; cc < 4; ++cc) {
            const int c0 = cc << 5;
            __syncthreads();
            #pragma unroll
            for (int q = 0; q < 4; ++q) {
                int f = (q << 8) + tid;            // float4 index 0..1023
                *(float4*)&Ws[4 * f] =
                    *(const float4*)&Wre[(size_t)k * (C_ * C_) + (size_t)c0 * C_ + 4 * f];
            }
            {   // gather: 2 threads/token, 16 channels each
                int tt = tid >> 1, half = tid & 1;
                int j = idxi[((size_t)b * N_ + n0 + tt) * K_ + k];
                const uint4* s4 = (const uint4*)(xb + (size_t)j * C_ + c0 + half * 16);
                #pragma unroll
                for (int qq = 0; qq < 2; ++qq) {
                    uint4 w = s4[qq];
                    int cr = half * 16 + qq * 8;
                    Gs[(cr + 0) * 132 + tt] = __uint_as_float(w.x << 16);
                    Gs[(cr + 1) * 132 + tt] = __uint_as_float(w.x & 0xffff0000u);
                    Gs[(cr + 2) * 132 + tt] = __uint_as_float(w.y << 16);
                    Gs[(cr + 3) * 132 + tt] = __uint_as_float(w.y & 0xffff0000u);
                    Gs[(cr + 4) * 132 + tt] = __uint_as_float(w.z << 16);
                    Gs[(cr + 5) * 132 + tt] = __uint_as_float(w.z & 0xffff0000u);
                    Gs[(cr + 6) * 132 + tt] = __uint_as_float(w.w << 16);
                    Gs[(cr + 7) * 132 + tt] = __uint_as_float(w.w & 0xffff0000u);
                }
            }
            __syncthreads();
            const float* Ap  = &Ws[8 * to];
            const float* Bp0 = &Gs[4 * tn];
            const float* Bp1 = &Gs[64 + 4 * tn];
            float4 a0 = *(const float4*)(Ap);
            float4 a1 = *(const float4*)(Ap + 4);
            float4 b0 = *(const float4*)(Bp0);
            float4 b1 = *(const float4*)(Bp1);
            #pragma unroll
            for (int c = 0; c < 32; ++c) {
                const int cn = (c + 1) & 31;
                float4 na0 = *(const float4*)(Ap  + cn * 128);
                float4 na1 = *(const float4*)(Ap  + cn * 128 + 4);
                float4 nb0 = *(const float4*)(Bp0 + cn * 132);
                float4 nb1 = *(const float4*)(Bp1 + cn * 132);
                float av[8] = {a0.x, a0.y, a0.z, a0.w, a1.x, a1.y, a1.z, a1.w};
                float bv[8] = {b0.x, b0.y, b0.z, b0.w, b1.x, b1.y, b1.z, b1.w};
                #pragma unroll
                for (int i = 0; i < 8; ++i)
                    #pragma unroll
                    for (int j = 0; j < 8; ++j)
                        acc[i][j] = fmaf(av[i], bv[j], acc[i][j]);
                a0 = na0; a1 = na1; b0 = nb0; b1 = nb1;
            }
        }
    }
    float* ob = out + (size_t)b * CN_;
    #pragma unroll
    for (int i = 0; i < 8; ++i) {
        float* rowp = ob + (size_t)(8 * to + i) * N_ + n0;
        #pragma unroll
        for (int j = 0; j < 4; ++j) unsafeAtomicAdd(rowp + 4 * tn + j,      acc[i][j]);
        #pragma unroll
        for (int j = 0; j < 4; ++j) unsafeAtomicAdd(rowp + 64 + 4 * tn + j, acc[i][4 + j]);
    }
}

// ---------------------------------------------------------------------------
extern "C" void kernel_launch(void* const* d_in, const int* in_sizes, int n_in,
                              void* d_out, int out_size, void* d_ws, size_t ws_size,
                              hipStream_t stream) {
    (void)in_sizes; (void)n_in; (void)ws_size;
    const float* x = (const float*)d_in[0];
    const float* W = (const float*)d_in[1];
    float* out = (float*)d_out;
    float* ws  = (float*)d_ws;

    float* xn  = ws + XN_OFF;
    float* cv  = ws + CV_OFF;
    int*   ci  = (int*)(ws + CI_OFF);
    __hip_bfloat16* xtb = (__hip_bfloat16*)(ws + CAND_OFF);  // aliases cv/ci (disjoint lifetime)
    float* Wre = ws + WRE_OFF;
    int*   idx = (int*)(ws + IDX_OFF);

    norm_xn_kernel<<<(B_ * N_) / TPB, TPB, 0, stream>>>(x, xn);
    wre_kernel<<<(K_ * C_ * C_) / TPB, TPB, 0, stream>>>(W, Wre);
    sim_gemm_kernel<<<B_ * 8 * 4, TPB, 0, stream>>>(xn, cv, ci);
    topk_merge_kernel<<<(B_ * N_) / TPB, TPB, 0, stream>>>(cv, ci, idx);
    transpose_bf16_kernel<<<B_ * 16, TPB, 0, stream>>>(x, xtb);  // after merge
    zero_out_kernel<<<1024, TPB, 0, stream>>>((float4*)out, out_size / 4);
    conv_kg_kernel<<<B_ * 8 * 3, TPB, 0, stream>>>(xtb, Wre, idx, out);
}

// Round 4
// 566.862 us; speedup vs baseline: 1.4531x; 1.0551x over previous
//
#include <hip/hip_runtime.h>
#include <hip/hip_bf16.h>

#define TPB 256

typedef float f32x4 __attribute__((ext_vector_type(4)));
typedef short s16x8 __attribute__((ext_vector_type(8)));

static constexpr int B_ = 32;
static constexpr int C_ = 128;
static constexpr int N_ = 1024;
static constexpr int K_ = 9;
static constexpr int CN_ = C_ * N_;
static constexpr float INFV = 1.0e10f;
static constexpr float EPS_ = 1e-8f;

// ws layout (float slots), total 6,995,968 floats = 28.0 MB
static constexpr size_t XN_OFF   = 0;                                // xn [B][C][N] fp32
static constexpr size_t CAND_OFF = (size_t)B_ * CN_;                 // cv|ci ; xtb bf16 aliases
static constexpr size_t CV_OFF   = CAND_OFF;                         // [B][N][4][9] float
static constexpr size_t CI_OFF   = CAND_OFF + (size_t)B_ * N_ * 36;  // [B][N][4][9] int
static constexpr size_t WBH_OFF  = CAND_OFF + 2 * (size_t)B_ * N_ * 36; // [K][128o][128c] bf16
static constexpr size_t WBL_OFF  = WBH_OFF + (size_t)K_ * C_ * C_ / 2;  // [K][128o][128c] bf16
static constexpr size_t IDX_OFF  = WBL_OFF + (size_t)K_ * C_ * C_ / 2;  // [B][N][9] int

__device__ __forceinline__ void gload_lds16(const void* g, void* l) {
    __builtin_amdgcn_global_load_lds((const __attribute__((address_space(1))) void*)g,
                                     (__attribute__((address_space(3))) void*)l, 16, 0, 0);
}

// exact stable top-9 insert
#define INSERT9(Vv, Ii, vexpr, gmexpr)                                     \
    {                                                                       \
        float _v = (vexpr); int _gm = (gmexpr);                             \
        bool bp[9];                                                         \
        _Pragma("unroll")                                                   \
        for (int _p = 0; _p < 9; ++_p)                                      \
            bp[_p] = (_v > Vv[_p]) || (_v == Vv[_p] && _gm < Ii[_p]);       \
        if (bp[8]) {                                                        \
            _Pragma("unroll")                                               \
            for (int _p = 8; _p >= 1; --_p) {                               \
                Vv[_p] = bp[_p - 1] ? Vv[_p - 1] : (bp[_p] ? _v  : Vv[_p]); \
                Ii[_p] = bp[_p - 1] ? Ii[_p - 1] : (bp[_p] ? _gm : Ii[_p]); \
            }                                                               \
            if (bp[0]) { Vv[0] = _v; Ii[0] = _gm; }                         \
        }                                                                   \
    }

// ---------------------------------------------------------------------------
// 1) xn = x / (||x||_channel + eps)
// ---------------------------------------------------------------------------
__global__ __launch_bounds__(TPB) void norm_xn_kernel(const float* __restrict__ x,
                                                      float* __restrict__ xn) {
    int t = blockIdx.x * TPB + threadIdx.x;
    int b = t >> 10, n = t & (N_ - 1);
    const float* p = x + (size_t)b * CN_ + n;
    float ss = 0.f;
    #pragma unroll 8
    for (int c = 0; c < C_; ++c) { float v = p[(size_t)c * N_]; ss += v * v; }
    float nrm = sqrtf(ss) + EPS_;
    float* q = xn + (size_t)b * CN_ + n;
    #pragma unroll 8
    for (int c = 0; c < C_; ++c) q[(size_t)c * N_] = p[(size_t)c * N_] / nrm;
}

// ---------------------------------------------------------------------------
// 2) xtb[b][n][c] = bf16(x[b][c][n])
// ---------------------------------------------------------------------------
__global__ __launch_bounds__(TPB) void transpose_bf16_kernel(const float* __restrict__ x,
                                                             __hip_bfloat16* __restrict__ xtb) {
    __shared__ float lds[128][65];
    int b = blockIdx.x >> 4, n0 = (blockIdx.x & 15) << 6;
    const float* src = x + (size_t)b * CN_ + n0;
    #pragma unroll 4
    for (int i = 0; i < 32; ++i) {
        int flat = i * TPB + threadIdx.x;
        int c = flat >> 6, nn = flat & 63;
        lds[c][nn] = src[(size_t)c * N_ + nn];
    }
    __syncthreads();
    __hip_bfloat16* dst = xtb + (size_t)b * CN_ + (size_t)n0 * C_;
    #pragma unroll 4
    for (int i = 0; i < 32; ++i) {
        int flat = i * TPB + threadIdx.x;
        int nn = flat >> 7, c = flat & 127;
        dst[(size_t)nn * C_ + c] = __float2bfloat16(lds[c][nn]);
    }
}

// ---------------------------------------------------------------------------
// 3) split-bf16 weights: wh/wl [k][o][c], wh+wl ~= W[o][c][k] (fp32)
// ---------------------------------------------------------------------------
__global__ __launch_bounds__(TPB) void wbprep_kernel(const float* __restrict__ W,
                                                     __hip_bfloat16* __restrict__ wh,
                                                     __hip_bfloat16* __restrict__ wl) {
    int t = blockIdx.x * TPB + threadIdx.x;          // 0..147455
    int k = t / (C_ * C_);
    int r = t - k * (C_ * C_);
    int o = r >> 7, c = r & 127;
    float w = W[((size_t)o * C_ + c) * K_ + k];
    __hip_bfloat16 h = __float2bfloat16(w);
    wh[t] = h;
    wl[t] = __float2bfloat16(w - __bfloat162float(h));
}

// ---------------------------------------------------------------------------
// 4) sim GEMM: gll-staged, double-buffered; FMA order bit-identical to r2/r3
// ---------------------------------------------------------------------------
__global__ __launch_bounds__(TPB, 2) void sim_gemm_kernel(const float* __restrict__ xn,
                                                          float* __restrict__ cv,
                                                          int* __restrict__ ci) {
    __shared__ __align__(16) float lds[16896];  // buf0 [0,8192) = As|Bs; buf1 [8192,16384); scanbuf [0,8448)
    __shared__ float mv[64][9];
    __shared__ int   mi[64][9];

    const int tid = threadIdx.x;
    const int lane = tid & 63;
    const int wv  = tid >> 6;
    const int jp = blockIdx.x & 3;
    const int it = (blockIdx.x >> 2) & 7;
    const int b  = blockIdx.x >> 5;
    const int n0 = it << 7;
    const float* xb = xn + (size_t)b * CN_;
    const int tr = tid >> 4, tc = tid & 15;
    const int rl = tid >> 1;
    const int sh = tid & 1;
    const int sg = tid >> 7;
    const int sr6 = rl & 63;
    const int grow = n0 + rl;

    float val[9]; int id[9];
    #pragma unroll
    for (int p = 0; p < 9; ++p) { val[p] = -1e30f; id[p] = -1; }

// stage one 32c chunk: As[32][128] <- xn rows @n0, Bs[32][128] <- rows @m0
#define SIM_STAGE(DST, C0, M0)                                                          \
    {                                                                                   \
        float* Ab_ = (DST);                                                             \
        float* Bb_ = (DST) + 4096;                                                      \
        _Pragma("unroll")                                                               \
        for (int q_ = 0; q_ < 4; ++q_) {                                                \
            int i_ = 4 * wv + q_;                                                       \
            const float* gr_ = xb + (size_t)((C0) + 2 * i_ + (lane >> 5)) * N_          \
                               + 4 * (lane & 31);                                       \
            gload_lds16(gr_ + n0,   &Ab_[i_ * 256]);                                    \
            gload_lds16(gr_ + (M0), &Bb_[i_ * 256]);                                    \
        }                                                                               \
    }

    #pragma unroll 1
    for (int ps = 0; ps < 2; ++ps) {
        const int m0 = ((jp << 1) + ps) << 7;
        float acc[8][8];
        #pragma unroll
        for (int i = 0; i < 8; ++i)
            #pragma unroll
            for (int j = 0; j < 8; ++j) acc[i][j] = 0.f;

        __syncthreads();                       // scan of prev ps fully done
        SIM_STAGE(lds, 0, m0);                 // prologue: cc=0 -> buf0
        __syncthreads();                       // drains vmcnt -> buf0 ready

        #pragma unroll 1
        for (int cc = 0; cc < 4; ++cc) {
            if (cc < 3) SIM_STAGE(lds + (((cc + 1) & 1) << 13), (cc + 1) << 5, m0);
            const float* cur = lds + ((cc & 1) << 13);
            const float* Ap  = cur + 8 * tr;
            const float* Bp0 = cur + 4096 + 4 * tc;
            const float* Bp1 = Bp0 + 64;
            float4 a0 = *(const float4*)(Ap);
            float4 a1 = *(const float4*)(Ap + 4);
            float4 b0 = *(const float4*)(Bp0);
            float4 b1 = *(const float4*)(Bp1);
            #pragma unroll
            for (int c = 0; c < 32; ++c) {
                const int cn = (c + 1) & 31;
                float4 na0 = *(const float4*)(Ap  + cn * 128);
                float4 na1 = *(const float4*)(Ap  + cn * 128 + 4);
                float4 nb0 = *(const float4*)(Bp0 + cn * 128);
                float4 nb1 = *(const float4*)(Bp1 + cn * 128);
                float av[8] = {a0.x, a0.y, a0.z, a0.w, a1.x, a1.y, a1.z, a1.w};
                float bv[8] = {b0.x, b0.y, b0.z, b0.w, b1.x, b1.y, b1.z, b1.w};
                #pragma unroll
                for (int i = 0; i < 8; ++i)
                    #pragma unroll
                    for (int j = 0; j < 8; ++j)
                        acc[i][j] = fmaf(av[i], bv[j], acc[i][j]);
                a0 = na0; a1 = na1; b0 = nb0; b1 = nb1;
            }
            __syncthreads();                   // all reads of cur done; next buf staged
        }

        // scan in two 64-row groups (identical logic to round 2/3)
        float* scanbuf = lds;
        #pragma unroll 1
        for (int g = 0; g < 2; ++g) {
            if ((tr >> 3) == g) {
                int rbase = (tr & 7) << 3;
                #pragma unroll
                for (int i = 0; i < 8; ++i) {
                    *(float4*)&scanbuf[(rbase + i) * 132 + 4 * tc] =
                        make_float4(acc[i][0], acc[i][1], acc[i][2], acc[i][3]);
                    *(float4*)&scanbuf[(rbase + i) * 132 + 64 + 4 * tc] =
                        make_float4(acc[i][4], acc[i][5], acc[i][6], acc[i][7]);
                }
            }
            __syncthreads();
            if (sg == g) {
                float lv[9]; int li[9];
                #pragma unroll
                for (int p = 0; p < 9; ++p) { lv[p] = -1e30f; li[p] = -1; }
                const float* srow = &scanbuf[sr6 * 132 + (sh << 6)];
                const int colbase = m0 + (sh << 6);
                for (int q = 0; q < 16; ++q) {
                    float4 v4 = *(const float4*)(srow + 4 * q);
                    const int gm0 = colbase + 4 * q;
                    float mx = fmaxf(fmaxf(v4.x, v4.y), fmaxf(v4.z, v4.w));
                    bool diag = ((unsigned)(grow - gm0) < 4u);
                    if (mx < lv[8] && !diag) continue;
                    float vv[4] = {v4.x, v4.y, v4.z, v4.w};
                    #pragma unroll
                    for (int j = 0; j < 4; ++j) {
                        float v = vv[j]; int gm = gm0 + j;
                        if (gm == grow) v = INFV;
                        INSERT9(lv, li, v, gm)
                    }
                }
                if (sh) {
                    #pragma unroll
                    for (int p = 0; p < 9; ++p) { mv[sr6][p] = lv[p]; mi[sr6][p] = li[p]; }
                } else {
                    #pragma unroll
                    for (int p = 0; p < 9; ++p) INSERT9(val, id, lv[p], li[p])
                }
            }
            __syncthreads();
            if (sg == g && sh == 0) {
                #pragma unroll
                for (int p = 0; p < 9; ++p) INSERT9(val, id, mv[sr6][p], mi[sr6][p])
            }
        }
    }

    if (sh == 0) {
        size_t base = (((size_t)b * N_ + grow) * 4 + jp) * 9;
        #pragma unroll
        for (int p = 0; p < 9; ++p) { cv[base + p] = val[p]; ci[base + p] = id[p]; }
    }
#undef SIM_STAGE
}

// ---------------------------------------------------------------------------
// 5) merge 4 partial top-9 lists -> final top-9 indices
// ---------------------------------------------------------------------------
__global__ __launch_bounds__(TPB) void topk_merge_kernel(const float* __restrict__ cv,
                                                         const int* __restrict__ ci,
                                                         int* __restrict__ idxo) {
    int t = blockIdx.x * TPB + threadIdx.x;
    float val[9]; int id[9];
    #pragma unroll
    for (int p = 0; p < 9; ++p) { val[p] = -1e30f; id[p] = -1; }
    const float* pv = cv + (size_t)t * 36;
    const int*   pi = ci + (size_t)t * 36;
    for (int s = 0; s < 36; ++s) {
        float v = pv[s]; int gm = pi[s];
        bool worse = (v < val[8]) || (v == val[8] && gm > id[8]);
        if (!worse) INSERT9(val, id, v, gm)
    }
    int* op = idxo + (size_t)t * 9;
    #pragma unroll
    for (int p = 0; p < 9; ++p) op[p] = id[p];
}

// ---------------------------------------------------------------------------
// 6) MFMA conv: per block 128o x 128n, K = 9k x 128c, split-bf16 weights
//    18 steps of (k, 64c-half), double-buffered gll staging, XOR-swizzled LDS
// ---------------------------------------------------------------------------
__global__ __launch_bounds__(TPB) void conv_mfma_kernel(const __hip_bfloat16* __restrict__ xtb,
                                                        const __hip_bfloat16* __restrict__ wbh,
                                                        const __hip_bfloat16* __restrict__ wbl,
                                                        const int* __restrict__ idxi,
                                                        float* __restrict__ out) {
    __shared__ __align__(16) __hip_bfloat16 gbuf[2][128 * 64];   // [tok][64c] swizzled
    __shared__ __align__(16) __hip_bfloat16 hbuf[2][128 * 64];   // [o][64c]  swizzled (W_hi)
    __shared__ __align__(16) __hip_bfloat16 lbuf[2][128 * 64];   // [o][64c]  swizzled (W_lo)
    __shared__ int ids[K_ * 128];

    const int tid = threadIdx.x;
    const int lane = tid & 63;
    const int wv = tid >> 6;
    const int b  = blockIdx.x >> 3;
    const int n0 = (blockIdx.x & 7) << 7;
    const __hip_bfloat16* xb = xtb + (size_t)b * CN_;

    for (int j = tid; j < K_ * 128; j += TPB) {
        int k = j >> 7, r = j & 127;
        ids[j] = idxi[((size_t)b * N_ + n0 + r) * K_ + k];
    }
    __syncthreads();

    f32x4 acc[2][8];
    #pragma unroll
    for (int mt = 0; mt < 2; ++mt)
        #pragma unroll
        for (int nt = 0; nt < 8; ++nt) acc[mt][nt] = (f32x4){0.f, 0.f, 0.f, 0.f};

    const int swz = ((lane & 7) ^ (lane >> 3)) * 8;   // source-swizzled bf16 offset (16B units)

// stage step S=(k,ch) into buffer PB: G rows=tokens, W rows=o; 12 gll per wave
#define CONV_STAGE(S, PB)                                                               \
    {                                                                                   \
        const int k_ = (S) >> 1, ch_ = ((S) & 1) * 64;                                  \
        _Pragma("unroll")                                                               \
        for (int q_ = 0; q_ < 4; ++q_) {                                                \
            int row_ = 32 * wv + 8 * q_ + (lane >> 3);                                  \
            int tok_ = ids[k_ * 128 + row_];                                            \
            gload_lds16(xb + (size_t)tok_ * C_ + ch_ + swz, &gbuf[PB][(32 * wv + 8 * q_) * 64]); \
            const size_t wr_ = ((size_t)k_ * 128 + row_) * C_ + ch_ + swz;              \
            gload_lds16(wbh + wr_, &hbuf[PB][(32 * wv + 8 * q_) * 64]);                 \
            gload_lds16(wbl + wr_, &lbuf[PB][(32 * wv + 8 * q_) * 64]);                 \
        }                                                                               \
    }

    CONV_STAGE(0, 0)
    __syncthreads();

    const int l15 = lane & 15, l7 = lane & 7, lq = lane >> 4;
    int pb = 0;
    #pragma unroll 1
    for (int s = 0; s < 18; ++s) {
        if (s < 17) CONV_STAGE(s + 1, pb ^ 1)
        const __hip_bfloat16* G = gbuf[pb];
        const __hip_bfloat16* H = hbuf[pb];
        const __hip_bfloat16* L = lbuf[pb];
        #pragma unroll
        for (int kc = 0; kc < 2; ++kc) {
            const int phys = ((kc * 4 + lq) ^ l7) * 8;   // swizzled 16B group, bf16 units
            s16x8 bb[8];
            #pragma unroll
            for (int nt = 0; nt < 8; ++nt)
                bb[nt] = *(const s16x8*)&G[(16 * nt + l15) * 64 + phys];
            #pragma unroll
            for (int mt = 0; mt < 2; ++mt) {
                const int orow = (32 * wv + 16 * mt + l15) * 64 + phys;
                s16x8 ah = *(const s16x8*)&H[orow];
                s16x8 al = *(const s16x8*)&L[orow];
                #pragma unroll
                for (int nt = 0; nt < 8; ++nt) {
                    acc[mt][nt] = __builtin_amdgcn_mfma_f32_16x16x32_bf16(ah, bb[nt], acc[mt][nt], 0, 0, 0);
                    acc[mt][nt] = __builtin_amdgcn_mfma_f32_16x16x32_bf16(al, bb[nt], acc[mt][nt], 0, 0, 0);
                }
            }
        }
        __syncthreads();     // drains gll (next buf ready) + all reads of pb done
        pb ^= 1;
    }

    // C-write: col = lane&15 -> n, row = (lane>>4)*4 + reg -> o   [verified m89 mapping]
    float* ob = out + (size_t)b * CN_;
    #pragma unroll
    for (int mt = 0; mt < 2; ++mt)
        #pragma unroll
        for (int nt = 0; nt < 8; ++nt) {
            int o = 32 * wv + 16 * mt + lq * 4;
            int n = n0 + 16 * nt + l15;
            #pragma unroll
            for (int r = 0; r < 4; ++r)
                ob[(size_t)(o + r) * N_ + n] = acc[mt][nt][r];
        }
#undef CONV_STAGE
}

// ---------------------------------------------------------------------------
extern "C" void kernel_launch(void* const* d_in, const int* in_sizes, int n_in,
                              void* d_out, int out_size, void* d_ws, size_t ws_size,
                              hipStream_t stream) {
    (void)in_sizes; (void)n_in; (void)out_size; (void)ws_size;
    const float* x = (const float*)d_in[0];
    const float* W = (const float*)d_in[1];
    float* out = (float*)d_out;
    float* ws  = (float*)d_ws;

    float* xn  = ws + XN_OFF;
    float* cv  = ws + CV_OFF;
    int*   ci  = (int*)(ws + CI_OFF);
    __hip_bfloat16* xtb = (__hip_bfloat16*)(ws + CAND_OFF);  // aliases cv/ci (disjoint lifetime)
    __hip_bfloat16* wbh = (__hip_bfloat16*)(ws + WBH_OFF);
    __hip_bfloat16* wbl = (__hip_bfloat16*)(ws + WBL_OFF);
    int*   idx = (int*)(ws + IDX_OFF);

    norm_xn_kernel<<<(B_ * N_) / TPB, TPB, 0, stream>>>(x, xn);
    wbprep_kernel<<<(K_ * C_ * C_) / TPB, TPB, 0, stream>>>(W, wbh, wbl);
    sim_gemm_kernel<<<B_ * 8 * 4, TPB, 0, stream>>>(xn, cv, ci);
    topk_merge_kernel<<<(B_ * N_) / TPB, TPB, 0, stream>>>(cv, ci, idx);
    transpose_bf16_kernel<<<B_ * 16, TPB, 0, stream>>>(x, xtb);  // after merge (alias)
    conv_mfma_kernel<<<B_ * 8, TPB, 0, stream>>>(xtb, wbh, wbl, idx, out);
}

// Round 5
// 379.604 us; speedup vs baseline: 2.1699x; 1.4933x over previous
//
#include <hip/hip_runtime.h>
#include <hip/hip_bf16.h>

#define TPB 256
#define STPB 512

typedef float f32x4 __attribute__((ext_vector_type(4)));
typedef short s16x8 __attribute__((ext_vector_type(8)));

static constexpr int B_ = 32;
static constexpr int C_ = 128;
static constexpr int N_ = 1024;
static constexpr int K_ = 9;
static constexpr int CN_ = C_ * N_;
static constexpr float INFV = 1.0e10f;
static constexpr float EPS_ = 1e-8f;

// ws layout (float slots)
static constexpr size_t XN_OFF   = 0;                                // xn [B][C][N] fp32
static constexpr size_t CAND_OFF = (size_t)B_ * CN_;                 // cv|ci ; xtb bf16 aliases
static constexpr size_t CV_OFF   = CAND_OFF;                         // [B][N][4][9] float
static constexpr size_t CI_OFF   = CAND_OFF + (size_t)B_ * N_ * 36;  // [B][N][4][9] int
static constexpr size_t WBH_OFF  = CAND_OFF + 2 * (size_t)B_ * N_ * 36; // [K][128o][128c] bf16
static constexpr size_t WBL_OFF  = WBH_OFF + (size_t)K_ * C_ * C_ / 2;  // [K][128o][128c] bf16
static constexpr size_t IDX_OFF  = WBL_OFF + (size_t)K_ * C_ * C_ / 2;  // [B][N][9] int

__device__ __forceinline__ void gload_lds16(const void* g, void* l) {
    __builtin_amdgcn_global_load_lds((const __attribute__((address_space(1))) void*)g,
                                     (__attribute__((address_space(3))) void*)l, 16, 0, 0);
}

// exact stable top-9 insert
#define INSERT9(Vv, Ii, vexpr, gmexpr)                                     \
    {                                                                       \
        float _v = (vexpr); int _gm = (gmexpr);                             \
        bool bp[9];                                                         \
        _Pragma("unroll")                                                   \
        for (int _p = 0; _p < 9; ++_p)                                      \
            bp[_p] = (_v > Vv[_p]) || (_v == Vv[_p] && _gm < Ii[_p]);       \
        if (bp[8]) {                                                        \
            _Pragma("unroll")                                               \
            for (int _p = 8; _p >= 1; --_p) {                               \
                Vv[_p] = bp[_p - 1] ? Vv[_p - 1] : (bp[_p] ? _v  : Vv[_p]); \
                Ii[_p] = bp[_p - 1] ? Ii[_p - 1] : (bp[_p] ? _gm : Ii[_p]); \
            }                                                               \
            if (bp[0]) { Vv[0] = _v; Ii[0] = _gm; }                         \
        }                                                                   \
    }

// ---------------------------------------------------------------------------
// 1) xn = x / (||x||_channel + eps)
// ---------------------------------------------------------------------------
__global__ __launch_bounds__(TPB) void norm_xn_kernel(const float* __restrict__ x,
                                                      float* __restrict__ xn) {
    int t = blockIdx.x * TPB + threadIdx.x;
    int b = t >> 10, n = t & (N_ - 1);
    const float* p = x + (size_t)b * CN_ + n;
    float ss = 0.f;
    #pragma unroll 8
    for (int c = 0; c < C_; ++c) { float v = p[(size_t)c * N_]; ss += v * v; }
    float nrm = sqrtf(ss) + EPS_;
    float* q = xn + (size_t)b * CN_ + n;
    #pragma unroll 8
    for (int c = 0; c < C_; ++c) q[(size_t)c * N_] = p[(size_t)c * N_] / nrm;
}

// ---------------------------------------------------------------------------
// 2) xtb[b][n][c] = bf16(x[b][c][n])
// ---------------------------------------------------------------------------
__global__ __launch_bounds__(TPB) void transpose_bf16_kernel(const float* __restrict__ x,
                                                             __hip_bfloat16* __restrict__ xtb) {
    __shared__ float lds[128][65];
    int b = blockIdx.x >> 4, n0 = (blockIdx.x & 15) << 6;
    const float* src = x + (size_t)b * CN_ + n0;
    #pragma unroll 4
    for (int i = 0; i < 32; ++i) {
        int flat = i * TPB + threadIdx.x;
        int c = flat >> 6, nn = flat & 63;
        lds[c][nn] = src[(size_t)c * N_ + nn];
    }
    __syncthreads();
    __hip_bfloat16* dst = xtb + (size_t)b * CN_ + (size_t)n0 * C_;
    #pragma unroll 4
    for (int i = 0; i < 32; ++i) {
        int flat = i * TPB + threadIdx.x;
        int nn = flat >> 7, c = flat & 127;
        dst[(size_t)nn * C_ + c] = __float2bfloat16(lds[c][nn]);
    }
}

// ---------------------------------------------------------------------------
// 3) split-bf16 weights: wh/wl [k][o][c], wh+wl ~= W[o][c][k] (fp32)
// ---------------------------------------------------------------------------
__global__ __launch_bounds__(TPB) void wbprep_kernel(const float* __restrict__ W,
                                                     __hip_bfloat16* __restrict__ wh,
                                                     __hip_bfloat16* __restrict__ wl) {
    int t = blockIdx.x * TPB + threadIdx.x;
    int k = t / (C_ * C_);
    int r = t - k * (C_ * C_);
    int o = r >> 7, c = r & 127;
    float w = W[((size_t)o * C_ + c) * K_ + k];
    __hip_bfloat16 h = __float2bfloat16(w);
    wh[t] = h;
    wl[t] = __float2bfloat16(w - __bfloat162float(h));
}

// ---------------------------------------------------------------------------
// 4) sim GEMM: 512 thr, 4x8/thread (acc=32 regs, no spill), gll double-buffer
//    FMA chain per (row,col) ascending c -> bitwise-identical sims to r2-r4
// ---------------------------------------------------------------------------
__global__ __launch_bounds__(STPB, 4) void sim_gemm_kernel(const float* __restrict__ xn,
                                                           float* __restrict__ cv,
                                                           int* __restrict__ ci) {
    __shared__ __align__(16) float lds[16896];   // buf0 [0,8192) buf1 [8192,16384); scanbuf [0,16896)
    __shared__ float mv[128][9];
    __shared__ int   mi[128][9];

    const int tid = threadIdx.x;
    const int lane = tid & 63;
    const int wv  = tid >> 6;                    // 0..7
    const int jp = blockIdx.x & 3;
    const int it = (blockIdx.x >> 2) & 7;
    const int b  = blockIdx.x >> 5;
    const int n0 = it << 7;
    const float* xb = xn + (size_t)b * CN_;
    const int tr = tid >> 4;                     // 0..31 (4 rows each)
    const int tc = tid & 15;                     // 0..15 (8 cols each)
    const int rl = tid >> 1;                     // scan row (tid<256)
    const int sh = tid & 1;
    const int grow = n0 + rl;

    float val[9]; int id[9];
    #pragma unroll
    for (int p = 0; p < 9; ++p) { val[p] = -1e30f; id[p] = -1; }

// stage one 32c chunk: waves 0-3 -> As[32][128] @n0, waves 4-7 -> Bs[32][128] @m0
#define SIM_STAGE(DST, C0, M0)                                                          \
    {                                                                                   \
        float* base_ = (DST) + ((wv >> 2) << 12);                                       \
        const int co_ = (wv >> 2) ? (M0) : n0;                                          \
        _Pragma("unroll")                                                               \
        for (int q_ = 0; q_ < 4; ++q_) {                                                \
            int i_ = ((wv & 3) << 2) + q_;                                              \
            const float* gr_ = xb + (size_t)((C0) + 2 * i_ + (lane >> 5)) * N_          \
                               + 4 * (lane & 31) + co_;                                 \
            gload_lds16(gr_, base_ + i_ * 256);                                         \
        }                                                                               \
    }

    #pragma unroll 1
    for (int ps = 0; ps < 2; ++ps) {
        const int m0 = ((jp << 1) + ps) << 7;
        float acc[4][8];
        #pragma unroll
        for (int i = 0; i < 4; ++i)
            #pragma unroll
            for (int j = 0; j < 8; ++j) acc[i][j] = 0.f;

        __syncthreads();                         // scanbuf reads of prev ps done
        SIM_STAGE(lds, 0, m0)                    // cc=0 -> buf0
        __syncthreads();                         // vmcnt drain: buf0 ready

        #pragma unroll 1
        for (int cc = 0; cc < 4; ++cc) {
            if (cc < 3) SIM_STAGE(lds + (((cc + 1) & 1) << 13), (cc + 1) << 5, m0)
            const float* cur = lds + ((cc & 1) << 13);
            const float* Ap  = cur + 4 * tr;
            const float* Bp0 = cur + 4096 + 4 * tc;
            const float* Bp1 = Bp0 + 64;
            float4 a0 = *(const float4*)(Ap);
            float4 b0 = *(const float4*)(Bp0);
            float4 b1 = *(const float4*)(Bp1);
            #pragma unroll
            for (int c = 0; c < 32; ++c) {
                const int cn = (c + 1) & 31;
                float4 na = *(const float4*)(Ap  + cn * 128);
                float4 nb0 = *(const float4*)(Bp0 + cn * 128);
                float4 nb1 = *(const float4*)(Bp1 + cn * 128);
                float av[4] = {a0.x, a0.y, a0.z, a0.w};
                float bv[8] = {b0.x, b0.y, b0.z, b0.w, b1.x, b1.y, b1.z, b1.w};
                #pragma unroll
                for (int i = 0; i < 4; ++i)
                    #pragma unroll
                    for (int j = 0; j < 8; ++j)
                        acc[i][j] = fmaf(av[i], bv[j], acc[i][j]);
                a0 = na; b0 = nb0; b1 = nb1;
            }
            __syncthreads();                     // reads of cur done; next buf staged
        }

        // dump all 128 rows -> scanbuf [128][132]
        float* scanbuf = lds;
        #pragma unroll
        for (int i = 0; i < 4; ++i) {
            int row = 4 * tr + i;
            *(float4*)&scanbuf[row * 132 + 4 * tc] =
                make_float4(acc[i][0], acc[i][1], acc[i][2], acc[i][3]);
            *(float4*)&scanbuf[row * 132 + 64 + 4 * tc] =
                make_float4(acc[i][4], acc[i][5], acc[i][6], acc[i][7]);
        }
        __syncthreads();

        if (tid < 256) {                         // 2 threads per row scan 64 cols each
            float lv[9]; int li[9];
            #pragma unroll
            for (int p = 0; p < 9; ++p) { lv[p] = -1e30f; li[p] = -1; }
            const float* srow = &scanbuf[rl * 132 + (sh << 6)];
            const int colbase = m0 + (sh << 6);
            for (int q = 0; q < 16; ++q) {
                float4 v4 = *(const float4*)(srow + 4 * q);
                const int gm0 = colbase + 4 * q;
                float mx = fmaxf(fmaxf(v4.x, v4.y), fmaxf(v4.z, v4.w));
                bool diag = ((unsigned)(grow - gm0) < 4u);
                if (mx < lv[8] && !diag) continue;
                float vv[4] = {v4.x, v4.y, v4.z, v4.w};
                #pragma unroll
                for (int j = 0; j < 4; ++j) {
                    float v = vv[j]; int gm = gm0 + j;
                    if (gm == grow) v = INFV;
                    INSERT9(lv, li, v, gm)
                }
            }
            if (sh) {
                #pragma unroll
                for (int p = 0; p < 9; ++p) { mv[rl][p] = lv[p]; mi[rl][p] = li[p]; }
            } else {
                #pragma unroll
                for (int p = 0; p < 9; ++p) INSERT9(val, id, lv[p], li[p])
            }
        }
        __syncthreads();
        if (tid < 256 && sh == 0) {
            #pragma unroll
            for (int p = 0; p < 9; ++p) INSERT9(val, id, mv[rl][p], mi[rl][p])
        }
    }

    if (tid < 256 && sh == 0) {
        size_t base = (((size_t)b * N_ + grow) * 4 + jp) * 9;
        #pragma unroll
        for (int p = 0; p < 9; ++p) { cv[base + p] = val[p]; ci[base + p] = id[p]; }
    }
#undef SIM_STAGE
}

// ---------------------------------------------------------------------------
// 5) merge 4 partial top-9 lists -> final top-9 indices
// ---------------------------------------------------------------------------
__global__ __launch_bounds__(TPB) void topk_merge_kernel(const float* __restrict__ cv,
                                                         const int* __restrict__ ci,
                                                         int* __restrict__ idxo) {
    int t = blockIdx.x * TPB + threadIdx.x;
    float val[9]; int id[9];
    #pragma unroll
    for (int p = 0; p < 9; ++p) { val[p] = -1e30f; id[p] = -1; }
    const float* pv = cv + (size_t)t * 36;
    const int*   pi = ci + (size_t)t * 36;
    for (int s = 0; s < 36; ++s) {
        float v = pv[s]; int gm = pi[s];
        bool worse = (v < val[8]) || (v == val[8] && gm > id[8]);
        if (!worse) INSERT9(val, id, v, gm)
    }
    int* op = idxo + (size_t)t * 9;
    #pragma unroll
    for (int p = 0; p < 9; ++p) op[p] = id[p];
}

// ---------------------------------------------------------------------------
// 6) MFMA conv: per block 128o x 128n, K = 9k x 128c, split-bf16 weights
// ---------------------------------------------------------------------------
__global__ __launch_bounds__(TPB) void conv_mfma_kernel(const __hip_bfloat16* __restrict__ xtb,
                                                        const __hip_bfloat16* __restrict__ wbh,
                                                        const __hip_bfloat16* __restrict__ wbl,
                                                        const int* __restrict__ idxi,
                                                        float* __restrict__ out) {
    __shared__ __align__(16) __hip_bfloat16 gbuf[2][128 * 64];
    __shared__ __align__(16) __hip_bfloat16 hbuf[2][128 * 64];
    __shared__ __align__(16) __hip_bfloat16 lbuf[2][128 * 64];
    __shared__ int ids[K_ * 128];

    const int tid = threadIdx.x;
    const int lane = tid & 63;
    const int wv = tid >> 6;
    const int b  = blockIdx.x >> 3;
    const int n0 = (blockIdx.x & 7) << 7;
    const __hip_bfloat16* xb = xtb + (size_t)b * CN_;

    for (int j = tid; j < K_ * 128; j += TPB) {
        int k = j >> 7, r = j & 127;
        ids[j] = idxi[((size_t)b * N_ + n0 + r) * K_ + k];
    }
    __syncthreads();

    f32x4 acc[2][8];
    #pragma unroll
    for (int mt = 0; mt < 2; ++mt)
        #pragma unroll
        for (int nt = 0; nt < 8; ++nt) acc[mt][nt] = (f32x4){0.f, 0.f, 0.f, 0.f};

    const int swz = ((lane & 7) ^ (lane >> 3)) * 8;

#define CONV_STAGE(S, PB)                                                               \
    {                                                                                   \
        const int k_ = (S) >> 1, ch_ = ((S) & 1) * 64;                                  \
        _Pragma("unroll")                                                               \
        for (int q_ = 0; q_ < 4; ++q_) {                                                \
            int row_ = 32 * wv + 8 * q_ + (lane >> 3);                                  \
            int tok_ = ids[k_ * 128 + row_];                                            \
            gload_lds16(xb + (size_t)tok_ * C_ + ch_ + swz, &gbuf[PB][(32 * wv + 8 * q_) * 64]); \
            const size_t wr_ = ((size_t)k_ * 128 + row_) * C_ + ch_ + swz;              \
            gload_lds16(wbh + wr_, &hbuf[PB][(32 * wv + 8 * q_) * 64]);                 \
            gload_lds16(wbl + wr_, &lbuf[PB][(32 * wv + 8 * q_) * 64]);                 \
        }                                                                               \
    }

    CONV_STAGE(0, 0)
    __syncthreads();

    const int l15 = lane & 15, l7 = lane & 7, lq = lane >> 4;
    int pb = 0;
    #pragma unroll 1
    for (int s = 0; s < 18; ++s) {
        if (s < 17) CONV_STAGE(s + 1, pb ^ 1)
        const __hip_bfloat16* G = gbuf[pb];
        const __hip_bfloat16* H = hbuf[pb];
        const __hip_bfloat16* L = lbuf[pb];
        #pragma unroll
        for (int kc = 0; kc < 2; ++kc) {
            const int phys = ((kc * 4 + lq) ^ l7) * 8;
            s16x8 bb[8];
            #pragma unroll
            for (int nt = 0; nt < 8; ++nt)
                bb[nt] = *(const s16x8*)&G[(16 * nt + l15) * 64 + phys];
            #pragma unroll
            for (int mt = 0; mt < 2; ++mt) {
                const int orow = (32 * wv + 16 * mt + l15) * 64 + phys;
                s16x8 ah = *(const s16x8*)&H[orow];
                s16x8 al = *(const s16x8*)&L[orow];
                #pragma unroll
                for (int nt = 0; nt < 8; ++nt) {
                    acc[mt][nt] = __builtin_amdgcn_mfma_f32_16x16x32_bf16(ah, bb[nt], acc[mt][nt], 0, 0, 0);
                    acc[mt][nt] = __builtin_amdgcn_mfma_f32_16x16x32_bf16(al, bb[nt], acc[mt][nt], 0, 0, 0);
                }
            }
        }
        __syncthreads();
        pb ^= 1;
    }

    float* ob = out + (size_t)b * CN_;
    #pragma unroll
    for (int mt = 0; mt < 2; ++mt)
        #pragma unroll
        for (int nt = 0; nt < 8; ++nt) {
            int o = 32 * wv + 16 * mt + lq * 4;
            int n = n0 + 16 * nt + l15;
            #pragma unroll
            for (int r = 0; r < 4; ++r)
                ob[(size_t)(o + r) * N_ + n] = acc[mt][nt][r];
        }
#undef CONV_STAGE
}

// ---------------------------------------------------------------------------
extern "C" void kernel_launch(void* const* d_in, const int* in_sizes, int n_in,
                              void* d_out, int out_size, void* d_ws, size_t ws_size,
                              hipStream_t stream) {
    (void)in_sizes; (void)n_in; (void)out_size; (void)ws_size;
    const float* x = (const float*)d_in[0];
    const float* W = (const float*)d_in[1];
    float* out = (float*)d_out;
    float* ws  = (float*)d_ws;

    float* xn  = ws + XN_OFF;
    float* cv  = ws + CV_OFF;
    int*   ci  = (int*)(ws + CI_OFF);
    __hip_bfloat16* xtb = (__hip_bfloat16*)(ws + CAND_OFF);  // aliases cv/ci (disjoint lifetime)
    __hip_bfloat16* wbh = (__hip_bfloat16*)(ws + WBH_OFF);
    __hip_bfloat16* wbl = (__hip_bfloat16*)(ws + WBL_OFF);
    int*   idx = (int*)(ws + IDX_OFF);

    norm_xn_kernel<<<(B_ * N_) / TPB, TPB, 0, stream>>>(x, xn);
    wbprep_kernel<<<(K_ * C_ * C_) / TPB, TPB, 0, stream>>>(W, wbh, wbl);
    sim_gemm_kernel<<<B_ * 8 * 4, STPB, 0, stream>>>(xn, cv, ci);
    topk_merge_kernel<<<(B_ * N_) / TPB, TPB, 0, stream>>>(cv, ci, idx);
    transpose_bf16_kernel<<<B_ * 16, TPB, 0, stream>>>(x, xtb);  // after merge (alias)
    conv_mfma_kernel<<<B_ * 8, TPB, 0, stream>>>(xtb, wbh, wbl, idx, out);
}